// Round 5
// baseline (117.650 us; speedup 1.0000x reference)
//
#include <hip/hip_runtime.h>
#include <hip/hip_fp16.h>
#include <math.h>

#define NUM_ENT 14541
#define NUM_REL2 474
#define EMBED_D 200
#define BATCH 256
#define GAMMA 9.0f

#define TILE 64
#define ROWW (EMBED_D / 2)          // 100 uints per fp16 row
#define NOCTS (EMBED_D / 8)         // 25 octs (16 B each) per row

#define ENT_OCTS (NUM_ENT * NOCTS)  // 363525
#define OBJ_OCTS (BATCH   * NOCTS)  // 6400

typedef _Float16 h2 __attribute__((ext_vector_type(2)));

__device__ __forceinline__ h2 habs2(h2 x) {
    unsigned u = __builtin_bit_cast(unsigned, x) & 0x7FFF7FFFu;
    return __builtin_bit_cast(h2, u);
}

// acc += sum_{8 dims} |ov - ev|   (pk_f16 sub + and-abs + v_dot2_f32_f16)
__device__ __forceinline__ float oct_l1(uint4 ov, uint4 ev, float acc, h2 ones) {
    h2 d;
    d = __builtin_bit_cast(h2, ov.x) - __builtin_bit_cast(h2, ev.x);
    acc = __builtin_amdgcn_fdot2(habs2(d), ones, acc, false);
    d = __builtin_bit_cast(h2, ov.y) - __builtin_bit_cast(h2, ev.y);
    acc = __builtin_amdgcn_fdot2(habs2(d), ones, acc, false);
    d = __builtin_bit_cast(h2, ov.z) - __builtin_bit_cast(h2, ev.z);
    acc = __builtin_amdgcn_fdot2(habs2(d), ones, acc, false);
    d = __builtin_bit_cast(h2, ov.w) - __builtin_bit_cast(h2, ev.w);
    acc = __builtin_amdgcn_fdot2(habs2(d), ones, acc, false);
    return acc;
}

// ---------------- prep: fp32 -> fp16 tables in d_ws ----------------
__global__ __launch_bounds__(256)
void prep_kernel(const float* __restrict__ ent, const float* __restrict__ relE,
                 const int* __restrict__ sub, const int* __restrict__ rel,
                 unsigned int* __restrict__ ent16, unsigned int* __restrict__ obj16)
{
    const int idx = blockIdx.x * 256 + threadIdx.x;
    if (idx < ENT_OCTS) {
        const int e = idx / NOCTS, o = idx - e * NOCTS;
        const float* p = ent + (size_t)e * EMBED_D + o * 8;
        const float4 a = *(const float4*)p;
        const float4 b = *(const float4*)(p + 4);
        uint4 v;
        v.x = __builtin_bit_cast(unsigned, __builtin_amdgcn_cvt_pkrtz(a.x, a.y));
        v.y = __builtin_bit_cast(unsigned, __builtin_amdgcn_cvt_pkrtz(a.z, a.w));
        v.z = __builtin_bit_cast(unsigned, __builtin_amdgcn_cvt_pkrtz(b.x, b.y));
        v.w = __builtin_bit_cast(unsigned, __builtin_amdgcn_cvt_pkrtz(b.z, b.w));
        *(uint4*)(ent16 + (size_t)idx * 4) = v;
    } else if (idx < ENT_OCTS + OBJ_OCTS) {
        const int k = idx - ENT_OCTS;
        const int bI = k / NOCTS, o = k - bI * NOCTS;
        const float* pa = ent  + (size_t)sub[bI] * EMBED_D + o * 8;
        const float* pr = relE + (size_t)rel[bI] * EMBED_D + o * 8;
        const float4 a0 = *(const float4*)pa;
        const float4 a1 = *(const float4*)(pa + 4);
        const float4 r0 = *(const float4*)pr;
        const float4 r1 = *(const float4*)(pr + 4);
        uint4 v;
        v.x = __builtin_bit_cast(unsigned, __builtin_amdgcn_cvt_pkrtz(a0.x + r0.x, a0.y + r0.y));
        v.y = __builtin_bit_cast(unsigned, __builtin_amdgcn_cvt_pkrtz(a0.z + r0.z, a0.w + r0.w));
        v.z = __builtin_bit_cast(unsigned, __builtin_amdgcn_cvt_pkrtz(a1.x + r1.x, a1.y + r1.y));
        v.w = __builtin_bit_cast(unsigned, __builtin_amdgcn_cvt_pkrtz(a1.z + r1.z, a1.w + r1.w));
        *(uint4*)(obj16 + (size_t)k * 4) = v;
    }
}

// ---------------- main ----------------
// 256 threads: tx = tid&15 (n), ty = tid>>4 (b, 0..15); micro-tile 4x4.
// obj tile staged ONCE in LDS (one barrier total); ent octs streamed
// global->register, software-pipelined one oct ahead.
__device__ __forceinline__ void load_ev(uint4 (&ev)[4],
                                        const unsigned* const (&p)[4], int boff) {
#pragma unroll
    for (int j = 0; j < 4; ++j)
        ev[j] = *(const uint4*)((const char*)p[j] + boff);
}

__device__ __forceinline__ void load_ov(uint4 (&ov)[4],
                                        const char* sbase, int boff) {
#pragma unroll
    for (int i = 0; i < 4; ++i)
        ov[i] = *(const uint4*)(sbase + i * (16 * ROWW * 4) + boff);
}

__device__ __forceinline__ void comp(float (&acc)[4][4], const uint4 (&ov)[4],
                                     const uint4 (&ev)[4], h2 ones) {
#pragma unroll
    for (int i = 0; i < 4; ++i)
#pragma unroll
        for (int j = 0; j < 4; ++j)
            acc[i][j] = oct_l1(ov[i], ev[j], acc[i][j], ones);
}

__global__ __launch_bounds__(256, 4)
void transe_main(const unsigned int* __restrict__ ent16,
                 const unsigned int* __restrict__ obj16,
                 float* __restrict__ out)
{
    __shared__ __align__(16) unsigned int objS[TILE * ROWW];   // 25600 B

    const int tid   = threadIdx.x;
    const int nbase = blockIdx.x * TILE;
    const int bbase = blockIdx.y * TILE;

    // stage obj tile once (contiguous, coalesced uint4 copy)
    for (int it = tid; it < TILE * ROWW / 4; it += 256)
        *(uint4*)&objS[it * 4] =
            *(const uint4*)(obj16 + (size_t)bbase * ROWW + it * 4);
    __syncthreads();

    const int tx = tid & 15, ty = tid >> 4;

    // ent row pointers (4 rows per thread), clamped; stores guarded in epilogue
    const unsigned* p[4];
#pragma unroll
    for (int j = 0; j < 4; ++j) {
        int r = nbase + tx + 16 * j;
        if (r >= NUM_ENT) r = NUM_ENT - 1;
        p[j] = ent16 + (size_t)r * ROWW;
    }
    const char* sbase = (const char*)&objS[ty * ROWW];

    float acc[4][4] = {};
    h2 ones; ones[0] = (_Float16)1.0f; ones[1] = (_Float16)1.0f;

    uint4 evA[4], ovA[4], evB[4], ovB[4];
    load_ev(evA, p, 0);
    load_ov(ovA, sbase, 0);

    int boff = 0;   // byte offset of oct A within row
#pragma unroll 1
    for (int o = 0; o < NOCTS - 1; o += 2) {
        load_ev(evB, p, boff + 16);
        load_ov(ovB, sbase, boff + 16);
        comp(acc, ovA, evA, ones);
        load_ev(evA, p, boff + 32);       // o+2 <= 24 always (o max 22)
        load_ov(ovA, sbase, boff + 32);
        comp(acc, ovB, evB, ones);
        boff += 32;
    }
    comp(acc, ovA, evA, ones);            // oct 24

    // epilogue: sigmoid(GAMMA - dist)
#pragma unroll
    for (int i = 0; i < 4; ++i) {
        const int b_g = bbase + ty + 16 * i;
#pragma unroll
        for (int j = 0; j < 4; ++j) {
            const int n_g = nbase + tx + 16 * j;
            if (n_g < NUM_ENT) {
                out[(size_t)b_g * NUM_ENT + n_g] =
                    1.0f / (1.0f + __expf(acc[i][j] - GAMMA));
            }
        }
    }
}

extern "C" void kernel_launch(void* const* d_in, const int* in_sizes, int n_in,
                              void* d_out, int out_size, void* d_ws, size_t ws_size,
                              hipStream_t stream) {
    const float* ent  = (const float*)d_in[0];
    const float* relE = (const float*)d_in[1];
    const int*   sub  = (const int*)d_in[2];
    const int*   rel  = (const int*)d_in[3];
    float* out = (float*)d_out;

    unsigned int* ent16 = (unsigned int*)d_ws;
    unsigned int* obj16 = ent16 + (size_t)ENT_OCTS * 4;

    const int prep_total = ENT_OCTS + OBJ_OCTS;
    prep_kernel<<<(prep_total + 255) / 256, 256, 0, stream>>>(ent, relE, sub, rel,
                                                              ent16, obj16);

    dim3 grid((NUM_ENT + TILE - 1) / TILE, BATCH / TILE);   // 228 x 4
    transe_main<<<grid, 256, 0, stream>>>(ent16, obj16, out);
}